// Round 1
// baseline (2155.518 us; speedup 1.0000x reference)
//
#include <hip/hip_runtime.h>
#include <hip/hip_bf16.h>
#include <math.h>

// Problem constants (B=4, T=2048, C=1024, H=16, HS=64)
#define BB 4
#define TT 2048
#define CC 1024
#define HH 16
#define HS 64
#define ROWS (BB*TT)          // 8192

// ---------------------------------------------------------------------------
// GEMM: C[M,N] = A[M,K] @ W[K,N] + bias[N]      (fp32, 128x128 tile, 8x8/thr)
// ---------------------------------------------------------------------------
#define GBM 128
#define GBN 128
#define GBK 16
#define GPAD 4    // LDS row stride 132 floats, keeps float4 alignment

__global__ __launch_bounds__(256) void gemm_bias_kernel(
    const float* __restrict__ A, const float* __restrict__ W,
    const float* __restrict__ bias, float* __restrict__ C,
    int M, int N, int K)
{
    __shared__ float As[GBK][GBM + GPAD];
    __shared__ float Ws[GBK][GBN + GPAD];
    const int tid = threadIdx.x;
    const int tx = tid & 15;        // N direction
    const int ty = tid >> 4;        // M direction
    const int row0 = blockIdx.y * GBM;
    const int col0 = blockIdx.x * GBN;

    float acc[8][8];
    #pragma unroll
    for (int i = 0; i < 8; ++i)
        #pragma unroll
        for (int j = 0; j < 8; ++j) acc[i][j] = 0.f;

    for (int k0 = 0; k0 < K; k0 += GBK) {
        // A tile: 128x16 = 512 float4 (4 float4 per row along K)
        #pragma unroll
        for (int l = 0; l < 2; ++l) {
            int idx = tid + l * 256;          // 0..511
            int m   = idx >> 2;               // 0..127
            int kq  = (idx & 3) << 2;         // 0,4,8,12
            const float4 a4 = *reinterpret_cast<const float4*>(
                &A[(size_t)(row0 + m) * K + k0 + kq]);
            As[kq + 0][m] = a4.x; As[kq + 1][m] = a4.y;
            As[kq + 2][m] = a4.z; As[kq + 3][m] = a4.w;
        }
        // W tile: 16x128 = 512 float4 (contiguous along N)
        #pragma unroll
        for (int l = 0; l < 2; ++l) {
            int idx = tid + l * 256;
            int kq  = idx >> 5;               // 0..15
            int n   = (idx & 31) << 2;        // 0..124
            const float4 w4 = *reinterpret_cast<const float4*>(
                &W[(size_t)(k0 + kq) * N + col0 + n]);
            Ws[kq][n + 0] = w4.x; Ws[kq][n + 1] = w4.y;
            Ws[kq][n + 2] = w4.z; Ws[kq][n + 3] = w4.w;
        }
        __syncthreads();
        #pragma unroll
        for (int k = 0; k < GBK; ++k) {
            float ra[8], rw[8];
            #pragma unroll
            for (int i = 0; i < 8; ++i) ra[i] = As[k][ty * 8 + i];
            #pragma unroll
            for (int j = 0; j < 8; ++j) rw[j] = Ws[k][tx * 8 + j];
            #pragma unroll
            for (int i = 0; i < 8; ++i)
                #pragma unroll
                for (int j = 0; j < 8; ++j) acc[i][j] += ra[i] * rw[j];
        }
        __syncthreads();
    }
    #pragma unroll
    for (int i = 0; i < 8; ++i) {
        int row = row0 + ty * 8 + i;
        #pragma unroll
        for (int j4 = 0; j4 < 2; ++j4) {
            int col = col0 + tx * 8 + j4 * 4;
            float4 o;
            o.x = acc[i][j4 * 4 + 0] + bias[col + 0];
            o.y = acc[i][j4 * 4 + 1] + bias[col + 1];
            o.z = acc[i][j4 * 4 + 2] + bias[col + 2];
            o.w = acc[i][j4 * 4 + 3] + bias[col + 3];
            *reinterpret_cast<float4*>(&C[(size_t)row * N + col]) = o;
        }
    }
}

// ---------------------------------------------------------------------------
// Gated value transform (in-place over vraw):
//   per (b,t,h):  v = (v + v@W1 + b1) * sigmoid(v@W2 + b2)
// ---------------------------------------------------------------------------
__global__ __launch_bounds__(256) void gate_kernel(
    float* __restrict__ v,                 // [ROWS, C], read+write in place
    const float* __restrict__ W1, const float* __restrict__ b1,
    const float* __restrict__ W2, const float* __restrict__ b2,
    int rows)
{
    __shared__ float W1s[64][65];
    __shared__ float W2s[64][65];
    __shared__ float b1s[64], b2s[64];
    __shared__ float vs[1024];
    const int tid = threadIdx.x;
    #pragma unroll
    for (int l = 0; l < 16; ++l) {
        int idx = tid + l * 256;           // 0..4095
        W1s[idx >> 6][idx & 63] = W1[idx];
        W2s[idx >> 6][idx & 63] = W2[idx];
    }
    if (tid < 64) { b1s[tid] = b1[tid]; b2s[tid] = b2[tid]; }

    const int d = tid & 63;
    for (int row = blockIdx.x; row < rows; row += gridDim.x) {
        __syncthreads();                   // protect vs (and W load, 1st iter)
        for (int l = tid; l < 1024; l += 256) vs[l] = v[(size_t)row * 1024 + l];
        __syncthreads();
        for (int h = tid >> 6; h < 16; h += 4) {
            const float* vh = &vs[h * 64];
            float a = b1s[d], g = b2s[d];
            #pragma unroll 8
            for (int k = 0; k < 64; ++k) {
                a += vh[k] * W1s[k][d];
                g += vh[k] * W2s[k][d];
            }
            float val = (vh[d] + a) * (1.f / (1.f + __expf(-g)));
            v[(size_t)row * 1024 + h * 64 + d] = val;
        }
    }
}

// ---------------------------------------------------------------------------
// Flash-style causal attention, one (b, h, 64-row q-block) per 256-thr block.
//   S = U @ X^T / 32 (causal), online softmax, O = P @ V, y = O / l
// ---------------------------------------------------------------------------
__global__ __launch_bounds__(256) void attn_kernel(
    const float* __restrict__ u, const float* __restrict__ x,
    const float* __restrict__ v, float* __restrict__ y)
{
    __shared__ float Us[64][65];
    __shared__ float Xs[64][65];
    __shared__ float Vs[64][65];
    __shared__ float Ss[64][65];
    __shared__ float m_s[64], l_s[64], scale_s[64];

    const int tid = threadIdx.x;
    const int qb = blockIdx.x;            // 0..31
    const int h  = blockIdx.y;            // 0..15
    const int b  = blockIdx.z;            // 0..3
    const int q0 = qb * 64;
    const size_t base = ((size_t)b * TT) * CC + (size_t)h * HS;

    // U tile (64 x 64)
    #pragma unroll
    for (int l = 0; l < 4; ++l) {
        int idx = tid + l * 256;          // 0..1023
        int r = idx >> 4;
        int c = (idx & 15) << 2;
        const float4 a4 = *reinterpret_cast<const float4*>(
            &u[base + (size_t)(q0 + r) * CC + c]);
        Us[r][c] = a4.x; Us[r][c + 1] = a4.y; Us[r][c + 2] = a4.z; Us[r][c + 3] = a4.w;
    }
    if (tid < 64) { m_s[tid] = -INFINITY; l_s[tid] = 0.f; }

    const int r0 = (tid >> 4) << 2;       // 4x4 subtile rows
    const int c0 = (tid & 15) << 2;       // 4x4 subtile cols
    const int rr = tid >> 2;              // softmax: 4 threads per row
    const int ks = (tid & 3) << 4;

    float O[4][4];
    #pragma unroll
    for (int i = 0; i < 4; ++i)
        #pragma unroll
        for (int j = 0; j < 4; ++j) O[i][j] = 0.f;

    for (int kt = 0; kt <= qb; ++kt) {
        const int k0t = kt * 64;
        __syncthreads();                  // prev PV done; U/m/l visible (1st it)
        #pragma unroll
        for (int l = 0; l < 4; ++l) {
            int idx = tid + l * 256;
            int r = idx >> 4;
            int c = (idx & 15) << 2;
            const float4 xa = *reinterpret_cast<const float4*>(
                &x[base + (size_t)(k0t + r) * CC + c]);
            Xs[r][c] = xa.x; Xs[r][c + 1] = xa.y; Xs[r][c + 2] = xa.z; Xs[r][c + 3] = xa.w;
            const float4 va = *reinterpret_cast<const float4*>(
                &v[base + (size_t)(k0t + r) * CC + c]);
            Vs[r][c] = va.x; Vs[r][c + 1] = va.y; Vs[r][c + 2] = va.z; Vs[r][c + 3] = va.w;
        }
        __syncthreads();

        // S = U @ X^T
        float s[4][4];
        #pragma unroll
        for (int i = 0; i < 4; ++i)
            #pragma unroll
            for (int j = 0; j < 4; ++j) s[i][j] = 0.f;
        #pragma unroll 8
        for (int d = 0; d < 64; ++d) {
            float ua[4], xa[4];
            #pragma unroll
            for (int i = 0; i < 4; ++i) ua[i] = Us[r0 + i][d];
            #pragma unroll
            for (int j = 0; j < 4; ++j) xa[j] = Xs[c0 + j][d];
            #pragma unroll
            for (int i = 0; i < 4; ++i)
                #pragma unroll
                for (int j = 0; j < 4; ++j) s[i][j] += ua[i] * xa[j];
        }
        #pragma unroll
        for (int i = 0; i < 4; ++i)
            #pragma unroll
            for (int j = 0; j < 4; ++j) {
                float val = s[i][j] * 0.03125f;   // 1/sqrt(1024)
                if (kt == qb && (c0 + j) > (r0 + i)) val = -1e30f;
                Ss[r0 + i][c0 + j] = val;
            }
        __syncthreads();

        // online softmax (4 lanes per row, shfl reduce)
        {
            float pv[16];
            float pmax = -1e30f;
            #pragma unroll
            for (int j = 0; j < 16; ++j) { pv[j] = Ss[rr][ks + j]; pmax = fmaxf(pmax, pv[j]); }
            pmax = fmaxf(pmax, __shfl_xor(pmax, 1));
            pmax = fmaxf(pmax, __shfl_xor(pmax, 2));
            float mold = m_s[rr];
            float mnew = fmaxf(mold, pmax);
            float sc   = __expf(mold - mnew);     // exp(-inf) = 0 on 1st tile
            float psum = 0.f;
            #pragma unroll
            for (int j = 0; j < 16; ++j) {
                float p = __expf(pv[j] - mnew);
                Ss[rr][ks + j] = p;
                psum += p;
            }
            psum += __shfl_xor(psum, 1);
            psum += __shfl_xor(psum, 2);
            if ((tid & 3) == 0) {
                l_s[rr] = l_s[rr] * sc + psum;
                m_s[rr] = mnew;
                scale_s[rr] = sc;
            }
        }
        __syncthreads();

        // O = O*scale + P @ V
        #pragma unroll
        for (int i = 0; i < 4; ++i) {
            float sc = scale_s[r0 + i];
            #pragma unroll
            for (int j = 0; j < 4; ++j) O[i][j] *= sc;
        }
        #pragma unroll 8
        for (int k = 0; k < 64; ++k) {
            float pa[4], va[4];
            #pragma unroll
            for (int i = 0; i < 4; ++i) pa[i] = Ss[r0 + i][k];
            #pragma unroll
            for (int j = 0; j < 4; ++j) va[j] = Vs[k][c0 + j];
            #pragma unroll
            for (int i = 0; i < 4; ++i)
                #pragma unroll
                for (int j = 0; j < 4; ++j) O[i][j] += pa[i] * va[j];
        }
    }

    #pragma unroll
    for (int i = 0; i < 4; ++i) {
        float inv = 1.f / l_s[r0 + i];
        float4 o4;
        o4.x = O[i][0] * inv; o4.y = O[i][1] * inv;
        o4.z = O[i][2] * inv; o4.w = O[i][3] * inv;
        *reinterpret_cast<float4*>(&y[base + (size_t)(q0 + r0 + i) * CC + c0]) = o4;
    }
}

// ---------------------------------------------------------------------------
extern "C" void kernel_launch(void* const* d_in, const int* in_sizes, int n_in,
                              void* d_out, int out_size, void* d_ws, size_t ws_size,
                              hipStream_t stream)
{
    (void)in_sizes; (void)n_in; (void)out_size; (void)ws_size;
    const float* x  = (const float*)d_in[0];
    const float* Wu = (const float*)d_in[1];
    const float* bu = (const float*)d_in[2];
    const float* Wv = (const float*)d_in[3];
    const float* bv = (const float*)d_in[4];
    const float* W1 = (const float*)d_in[5];
    const float* b1 = (const float*)d_in[6];
    const float* W2 = (const float*)d_in[7];
    const float* b2 = (const float*)d_in[8];
    const float* Wp = (const float*)d_in[9];
    const float* bp = (const float*)d_in[10];
    float* out = (float*)d_out;

    float* u  = (float*)d_ws;                       // 32 MB
    float* v  = u + (size_t)ROWS * CC;              // 32 MB (gated in place)
    float* y  = v + (size_t)ROWS * CC;              // 32 MB

    dim3 gemm_grid(CC / GBN, ROWS / GBM);           // (8, 64)
    gemm_bias_kernel<<<gemm_grid, 256, 0, stream>>>(x, Wu, bu, u, ROWS, CC, CC);
    gemm_bias_kernel<<<gemm_grid, 256, 0, stream>>>(x, Wv, bv, v, ROWS, CC, CC);
    gate_kernel<<<2048, 256, 0, stream>>>(v, W1, b1, W2, b2, ROWS);
    attn_kernel<<<dim3(TT / 64, HH, BB), 256, 0, stream>>>(u, x, v, y);
    gemm_bias_kernel<<<gemm_grid, 256, 0, stream>>>(y, Wp, bp, out, ROWS, CC, CC);
}

// Round 2
// 1221.548 us; speedup vs baseline: 1.7646x; 1.7646x over previous
//
#include <hip/hip_runtime.h>
#include <hip/hip_bf16.h>
#include <math.h>

// Problem constants (B=4, T=2048, C=1024, H=16, HS=64)
#define BB 4
#define TT 2048
#define CC 1024
#define HH 16
#define HS 64
#define ROWS (BB*TT)          // 8192

typedef __bf16 bf16_t;
typedef __bf16 bf16x8 __attribute__((ext_vector_type(8)));
typedef __bf16 bf16x2 __attribute__((ext_vector_type(2)));
typedef float  f32x4  __attribute__((ext_vector_type(4)));

// ---------------------------------------------------------------------------
// GEMM: C[M,N] = A[M,K] @ W[K,N] + bias[N]      (fp32, 128x128 tile, 8x8/thr)
// ---------------------------------------------------------------------------
#define GBM 128
#define GBN 128
#define GBK 16
#define GPAD 4

__global__ __launch_bounds__(256) void gemm_bias_kernel(
    const float* __restrict__ A, const float* __restrict__ W,
    const float* __restrict__ bias, float* __restrict__ C,
    int M, int N, int K)
{
    __shared__ float As[GBK][GBM + GPAD];
    __shared__ float Ws[GBK][GBN + GPAD];
    const int tid = threadIdx.x;
    const int tx = tid & 15;
    const int ty = tid >> 4;
    const int row0 = blockIdx.y * GBM;
    const int col0 = blockIdx.x * GBN;

    float acc[8][8];
    #pragma unroll
    for (int i = 0; i < 8; ++i)
        #pragma unroll
        for (int j = 0; j < 8; ++j) acc[i][j] = 0.f;

    for (int k0 = 0; k0 < K; k0 += GBK) {
        #pragma unroll
        for (int l = 0; l < 2; ++l) {
            int idx = tid + l * 256;
            int m   = idx >> 2;
            int kq  = (idx & 3) << 2;
            const float4 a4 = *reinterpret_cast<const float4*>(
                &A[(size_t)(row0 + m) * K + k0 + kq]);
            As[kq + 0][m] = a4.x; As[kq + 1][m] = a4.y;
            As[kq + 2][m] = a4.z; As[kq + 3][m] = a4.w;
        }
        #pragma unroll
        for (int l = 0; l < 2; ++l) {
            int idx = tid + l * 256;
            int kq  = idx >> 5;
            int n   = (idx & 31) << 2;
            const float4 w4 = *reinterpret_cast<const float4*>(
                &W[(size_t)(k0 + kq) * N + col0 + n]);
            Ws[kq][n + 0] = w4.x; Ws[kq][n + 1] = w4.y;
            Ws[kq][n + 2] = w4.z; Ws[kq][n + 3] = w4.w;
        }
        __syncthreads();
        #pragma unroll
        for (int k = 0; k < GBK; ++k) {
            float ra[8], rw[8];
            #pragma unroll
            for (int i = 0; i < 8; ++i) ra[i] = As[k][ty * 8 + i];
            #pragma unroll
            for (int j = 0; j < 8; ++j) rw[j] = Ws[k][tx * 8 + j];
            #pragma unroll
            for (int i = 0; i < 8; ++i)
                #pragma unroll
                for (int j = 0; j < 8; ++j) acc[i][j] += ra[i] * rw[j];
        }
        __syncthreads();
    }
    #pragma unroll
    for (int i = 0; i < 8; ++i) {
        int row = row0 + ty * 8 + i;
        #pragma unroll
        for (int j4 = 0; j4 < 2; ++j4) {
            int col = col0 + tx * 8 + j4 * 4;
            float4 o;
            o.x = acc[i][j4 * 4 + 0] + bias[col + 0];
            o.y = acc[i][j4 * 4 + 1] + bias[col + 1];
            o.z = acc[i][j4 * 4 + 2] + bias[col + 2];
            o.w = acc[i][j4 * 4 + 3] + bias[col + 3];
            *reinterpret_cast<float4*>(&C[(size_t)row * N + col]) = o;
        }
    }
}

// ---------------------------------------------------------------------------
// Gated value transform (in-place):  v = (v + v@W1 + b1) * sigmoid(v@W2 + b2)
// ---------------------------------------------------------------------------
__global__ __launch_bounds__(256) void gate_kernel(
    float* __restrict__ v,
    const float* __restrict__ W1, const float* __restrict__ b1,
    const float* __restrict__ W2, const float* __restrict__ b2,
    int rows)
{
    __shared__ float W1s[64][65];
    __shared__ float W2s[64][65];
    __shared__ float b1s[64], b2s[64];
    __shared__ float vs[1024];
    const int tid = threadIdx.x;
    #pragma unroll
    for (int l = 0; l < 16; ++l) {
        int idx = tid + l * 256;
        W1s[idx >> 6][idx & 63] = W1[idx];
        W2s[idx >> 6][idx & 63] = W2[idx];
    }
    if (tid < 64) { b1s[tid] = b1[tid]; b2s[tid] = b2[tid]; }

    const int d = tid & 63;
    for (int row = blockIdx.x; row < rows; row += gridDim.x) {
        __syncthreads();
        for (int l = tid; l < 1024; l += 256) vs[l] = v[(size_t)row * 1024 + l];
        __syncthreads();
        for (int h = tid >> 6; h < 16; h += 4) {
            const float* vh = &vs[h * 64];
            float a = b1s[d], g = b2s[d];
            #pragma unroll 8
            for (int k = 0; k < 64; ++k) {
                a += vh[k] * W1s[k][d];
                g += vh[k] * W2s[k][d];
            }
            float val = (vh[d] + a) * (1.f / (1.f + __expf(-g)));
            v[(size_t)row * 1024 + h * 64 + d] = val;
        }
    }
}

// ---------------------------------------------------------------------------
// Pack: x,u,v (fp32 [B,T,C]) -> xb,ub [B,H,T,64] bf16 ; vbT [B,H,64,T] bf16
// One block per (b, h, 64-row t-tile).
// ---------------------------------------------------------------------------
__global__ __launch_bounds__(256) void pack_kernel(
    const float* __restrict__ x, const float* __restrict__ u,
    const float* __restrict__ v,
    bf16_t* __restrict__ xb, bf16_t* __restrict__ ub, bf16_t* __restrict__ vbT)
{
    __shared__ float vs[64][65];
    const int tid = threadIdx.x;
    const int t0 = blockIdx.x * 64;
    const int h = blockIdx.y, b = blockIdx.z;
    const int c2 = (tid & 31) * 2;   // even column
    const int r  = tid >> 5;         // 0..7

    #pragma unroll
    for (int rr = r; rr < 64; rr += 8) {
        size_t src = ((size_t)b * TT + t0 + rr) * CC + (size_t)h * HS + c2;
        float2 xv = *reinterpret_cast<const float2*>(&x[src]);
        float2 uv = *reinterpret_cast<const float2*>(&u[src]);
        float2 vv = *reinterpret_cast<const float2*>(&v[src]);
        size_t dst = ((size_t)(b * HH + h) * TT + t0 + rr) * HS + c2;
        bf16x2 t;
        t[0] = (bf16_t)xv.x; t[1] = (bf16_t)xv.y;
        *reinterpret_cast<bf16x2*>(&xb[dst]) = t;
        t[0] = (bf16_t)uv.x; t[1] = (bf16_t)uv.y;
        *reinterpret_cast<bf16x2*>(&ub[dst]) = t;
        vs[rr][c2] = vv.x; vs[rr][c2 + 1] = vv.y;
    }
    __syncthreads();
    #pragma unroll
    for (int d = r; d < 64; d += 8) {
        bf16x2 t;
        t[0] = (bf16_t)vs[c2][d];
        t[1] = (bf16_t)vs[c2 + 1][d];
        *reinterpret_cast<bf16x2*>(
            &vbT[((size_t)(b * HH + h) * HS + d) * TT + t0 + c2]) = t;
    }
}

// ---------------------------------------------------------------------------
// MFMA flash attention: one block = (b, h, 64-row q-block), 4 independent
// waves x 16 q-rows. K/V fragments straight from global (L2-resident,
// 256 KB/head). P goes D-layout -> A-layout via per-wave padded LDS tile.
// ---------------------------------------------------------------------------
__global__ __launch_bounds__(256) void attn_mfma_kernel(
    const bf16_t* __restrict__ ub, const bf16_t* __restrict__ xb,
    const bf16_t* __restrict__ vbT, float* __restrict__ y)
{
    __shared__ __align__(16) bf16_t Plds[2][4][16][72];
    const int tid  = threadIdx.x;
    const int wave = tid >> 6;
    const int lane = tid & 63;
    const int qb = (int)(gridDim.x - 1 - blockIdx.x);   // heavy blocks first
    const int h = blockIdx.y, b = blockIdx.z;
    const int q0 = qb * 64 + wave * 16;                 // wave's first q row
    const size_t hQK = (size_t)(b * HH + h) * TT * HS;
    const size_t hVT = (size_t)(b * HH + h) * HS * TT;

    const int lr = lane & 15;          // fragment row
    const int lk = (lane >> 4) * 8;    // fragment k offset

    // Q fragments for d-chunks 0 and 32 (rows q0+lr)
    const bf16x8 qf0 = *reinterpret_cast<const bf16x8*>(
        &ub[hQK + (size_t)(q0 + lr) * HS + lk]);
    const bf16x8 qf1 = *reinterpret_cast<const bf16x8*>(
        &ub[hQK + (size_t)(q0 + lr) * HS + 32 + lk]);

    f32x4 O[4];
    #pragma unroll
    for (int dt = 0; dt < 4; ++dt) O[dt] = (f32x4){0.f, 0.f, 0.f, 0.f};
    float m[4], lsum[4];
    #pragma unroll
    for (int j = 0; j < 4; ++j) { m[j] = -1e30f; lsum[j] = 0.f; }

    for (int kt = 0; kt <= qb; ++kt) {
        const int k0 = kt * 64;
        // S = U @ X^T  (4 column tiles of 16 keys)
        f32x4 S[4];
        #pragma unroll
        for (int nt = 0; nt < 4; ++nt) {
            f32x4 s = (f32x4){0.f, 0.f, 0.f, 0.f};
            const bf16_t* kp = &xb[hQK + (size_t)(k0 + nt * 16 + lr) * HS + lk];
            s = __builtin_amdgcn_mfma_f32_16x16x32_bf16(
                    qf0, *reinterpret_cast<const bf16x8*>(kp), s, 0, 0, 0);
            s = __builtin_amdgcn_mfma_f32_16x16x32_bf16(
                    qf1, *reinterpret_cast<const bf16x8*>(kp + 32), s, 0, 0, 0);
            S[nt] = s;
        }

        const bool diag = (kt == qb);
        const int pb = kt & 1;
        // scale + causal mask + online softmax (row = (lane>>4)*4+j)
        #pragma unroll
        for (int j = 0; j < 4; ++j) {
            const int qr = q0 + (lane >> 4) * 4 + j;
            float mx = -1e30f;
            #pragma unroll
            for (int nt = 0; nt < 4; ++nt) {
                float val = S[nt][j] * 0.03125f;   // 1/sqrt(1024)
                int kc = k0 + nt * 16 + lr;
                if (diag && kc > qr) val = -1e30f;
                S[nt][j] = val;
                mx = fmaxf(mx, val);
            }
            mx = fmaxf(mx, __shfl_xor(mx, 1));
            mx = fmaxf(mx, __shfl_xor(mx, 2));
            mx = fmaxf(mx, __shfl_xor(mx, 4));
            mx = fmaxf(mx, __shfl_xor(mx, 8));
            const float mnew = fmaxf(m[j], mx);
            const float sc = __expf(m[j] - mnew);
            float psum = 0.f;
            #pragma unroll
            for (int nt = 0; nt < 4; ++nt) {
                float p = __expf(S[nt][j] - mnew);
                psum += p;
                Plds[pb][wave][(lane >> 4) * 4 + j][nt * 16 + lr] = (bf16_t)p;
            }
            psum += __shfl_xor(psum, 1);
            psum += __shfl_xor(psum, 2);
            psum += __shfl_xor(psum, 4);
            psum += __shfl_xor(psum, 8);
            lsum[j] = lsum[j] * sc + psum;
            m[j] = mnew;
            #pragma unroll
            for (int dt = 0; dt < 4; ++dt) O[dt][j] *= sc;
        }
        __syncthreads();   // P writes -> P fragment reads (all waves same trip count)

        // O += P @ V   (A-frag from LDS, B-frag from vbT: k-contiguous)
        #pragma unroll
        for (int c = 0; c < 2; ++c) {
            const bf16x8 pf = *reinterpret_cast<const bf16x8*>(
                &Plds[pb][wave][lr][c * 32 + lk]);
            #pragma unroll
            for (int dt = 0; dt < 4; ++dt) {
                const bf16_t* vp =
                    &vbT[hVT + (size_t)(dt * 16 + lr) * TT + k0 + c * 32 + lk];
                O[dt] = __builtin_amdgcn_mfma_f32_16x16x32_bf16(
                    pf, *reinterpret_cast<const bf16x8*>(vp), O[dt], 0, 0, 0);
            }
        }
    }

    // epilogue: y[b, q, h*64+d] = O / l
    #pragma unroll
    for (int j = 0; j < 4; ++j) {
        const float inv = 1.f / lsum[j];
        const int qr = q0 + (lane >> 4) * 4 + j;
        const size_t base = ((size_t)b * TT + qr) * CC + (size_t)h * HS;
        #pragma unroll
        for (int dt = 0; dt < 4; ++dt)
            y[base + dt * 16 + lr] = O[dt][j] * inv;
    }
}

// ---------------------------------------------------------------------------
extern "C" void kernel_launch(void* const* d_in, const int* in_sizes, int n_in,
                              void* d_out, int out_size, void* d_ws, size_t ws_size,
                              hipStream_t stream)
{
    (void)in_sizes; (void)n_in; (void)out_size; (void)ws_size;
    const float* x  = (const float*)d_in[0];
    const float* Wu = (const float*)d_in[1];
    const float* bu = (const float*)d_in[2];
    const float* Wv = (const float*)d_in[3];
    const float* bv = (const float*)d_in[4];
    const float* W1 = (const float*)d_in[5];
    const float* b1 = (const float*)d_in[6];
    const float* W2 = (const float*)d_in[7];
    const float* b2 = (const float*)d_in[8];
    const float* Wp = (const float*)d_in[9];
    const float* bp = (const float*)d_in[10];
    float* out = (float*)d_out;

    const size_t NE = (size_t)ROWS * CC;            // 8.39M elements
    float*  u   = (float*)d_ws;                     // 32 MB
    float*  v   = u + NE;                           // 32 MB
    bf16_t* xb  = (bf16_t*)(v + NE);                // 16 MB
    bf16_t* ubb = xb + NE;                          // 16 MB
    bf16_t* vbT = ubb + NE;                         // 16 MB
    float*  y   = u;                                // alias: u dead after pack

    dim3 gemm_grid(CC / GBN, ROWS / GBM);           // (8, 64)
    gemm_bias_kernel<<<gemm_grid, 256, 0, stream>>>(x, Wu, bu, u, ROWS, CC, CC);
    gemm_bias_kernel<<<gemm_grid, 256, 0, stream>>>(x, Wv, bv, v, ROWS, CC, CC);
    gate_kernel<<<2048, 256, 0, stream>>>(v, W1, b1, W2, b2, ROWS);
    pack_kernel<<<dim3(TT / 64, HH, BB), 256, 0, stream>>>(x, u, v, xb, ubb, vbT);
    attn_mfma_kernel<<<dim3(TT / 64, HH, BB), 256, 0, stream>>>(ubb, xb, vbT, y);
    gemm_bias_kernel<<<gemm_grid, 256, 0, stream>>>(y, Wp, bp, out, ROWS, CC, CC);
}

// Round 3
// 456.352 us; speedup vs baseline: 4.7234x; 2.6768x over previous
//
#include <hip/hip_runtime.h>
#include <hip/hip_bf16.h>
#include <math.h>

// Problem constants (B=4, T=2048, C=1024, H=16, HS=64)
#define BB 4
#define TT 2048
#define CC 1024
#define HH 16
#define HS 64
#define ROWS (BB*TT)          // 8192

typedef __bf16 bf16_t;
typedef __bf16 bf16x8 __attribute__((ext_vector_type(8)));
typedef __bf16 bf16x2 __attribute__((ext_vector_type(2)));
typedef float  f32x4  __attribute__((ext_vector_type(4)));

// async global->LDS, 16B per lane; LDS dest is wave-uniform base + lane*16
#define GLDS16(g, l) __builtin_amdgcn_global_load_lds( \
    (const __attribute__((address_space(1))) void*)(g), \
    (__attribute__((address_space(3))) void*)(l), 16, 0, 0)

// ---------------------------------------------------------------------------
// fp32 -> bf16 convert (linear)
// ---------------------------------------------------------------------------
__global__ __launch_bounds__(256) void conv_x_kernel(
    const float* __restrict__ x, bf16_t* __restrict__ xbf)
{
    const size_t i = ((size_t)blockIdx.x * 256 + threadIdx.x) * 8;
    const float4 a = *reinterpret_cast<const float4*>(&x[i]);
    const float4 b = *reinterpret_cast<const float4*>(&x[i + 4]);
    bf16x8 o;
    o[0] = (bf16_t)a.x; o[1] = (bf16_t)a.y; o[2] = (bf16_t)a.z; o[3] = (bf16_t)a.w;
    o[4] = (bf16_t)b.x; o[5] = (bf16_t)b.y; o[6] = (bf16_t)b.z; o[7] = (bf16_t)b.w;
    *reinterpret_cast<bf16x8*>(&xbf[i]) = o;
}

// ---------------------------------------------------------------------------
// Weight transpose + convert:  Wt[n][k] = (bf16) W[k][n]     (1024x1024)
// ---------------------------------------------------------------------------
__global__ __launch_bounds__(256) void conv_wt_kernel(
    const float* __restrict__ W, bf16_t* __restrict__ Wt)
{
    __shared__ float t[64][65];
    const int tid = threadIdx.x;
    const int r0 = blockIdx.y * 64, c0 = blockIdx.x * 64;
    #pragma unroll
    for (int l = 0; l < 16; ++l) {
        int idx = tid + l * 256;            // 0..4095
        int rr = idx >> 6, cc = idx & 63;
        t[rr][cc] = W[(size_t)(r0 + rr) * CC + c0 + cc];
    }
    __syncthreads();
    #pragma unroll
    for (int l = 0; l < 16; ++l) {
        int idx = tid + l * 256;
        int rr = idx >> 6, cc = idx & 63;
        Wt[(size_t)(c0 + rr) * CC + r0 + cc] = (bf16_t)t[cc][rr];
    }
}

// ---------------------------------------------------------------------------
// MFMA GEMM (m97 structure): C[M,1024] = A[M,1024] @ W + bias
//   A bf16 row-major, Bt bf16 [N][K] (pre-transposed weight).
//   128x128 tile, BK=64, global_load_lds w=16, XOR-swizzled LDS (rule 21).
//   MODE 0: Cout = fp32 [M,1024].   MODE 1: Cout = bf16 packed [B,H,T,64].
// ---------------------------------------------------------------------------
template<int MODE>
__global__ __launch_bounds__(256) void mfma_gemm_kernel(
    const bf16_t* __restrict__ A, const bf16_t* __restrict__ Bt,
    const float* __restrict__ bias, void* __restrict__ Cout)
{
    __shared__ uint32_t smem[(16384 + 16384) / 4];
    char* const sA = (char*)smem;            // [128 m][64 k] bf16, swizzled
    char* const sB = (char*)smem + 16384;    // [128 n][64 k] bf16, swizzled
    const int tid = threadIdx.x;
    const int wave = tid >> 6, lane = tid & 63;
    const int row0 = blockIdx.y * 128, col0 = blockIdx.x * 128;
    const int wr = wave >> 1, wc = wave & 1;
    const int lr = lane & 15, ko = lane >> 4;
    const int xorv = (lr & 7) << 4;                      // read-side swizzle
    const int koff = ((lane & 7) ^ (lane >> 3)) << 3;    // staging inverse swz
    const int mloc8 = lane >> 3;                         // staging row-in-8

    f32x4 acc[4][4];
    #pragma unroll
    for (int i = 0; i < 4; ++i)
        #pragma unroll
        for (int j = 0; j < 4; ++j) acc[i][j] = (f32x4){0.f, 0.f, 0.f, 0.f};

    for (int k0 = 0; k0 < 1024; k0 += 64) {
        if (k0) __syncthreads();
        #pragma unroll
        for (int a = 0; a < 4; ++a) {
            const int m = wave * 32 + a * 8 + mloc8;     // 0..127, each once
            GLDS16(A  + (size_t)(row0 + m) * CC + k0 + koff,
                   sA + (wave * 4 + a) * 1024);
            GLDS16(Bt + (size_t)(col0 + m) * CC + k0 + koff,
                   sB + (wave * 4 + a) * 1024);
        }
        asm volatile("s_waitcnt vmcnt(0)" ::: "memory");
        __syncthreads();
        #pragma unroll
        for (int ks = 0; ks < 2; ++ks) {
            bf16x8 af[4], bf[4];
            const int kb = (ks * 64 + ko * 16) ^ xorv;
            #pragma unroll
            for (int mi = 0; mi < 4; ++mi)
                af[mi] = *reinterpret_cast<const bf16x8*>(
                    sA + (wr * 64 + mi * 16 + lr) * 128 + kb);
            #pragma unroll
            for (int ni = 0; ni < 4; ++ni)
                bf[ni] = *reinterpret_cast<const bf16x8*>(
                    sB + (wc * 64 + ni * 16 + lr) * 128 + kb);
            #pragma unroll
            for (int mi = 0; mi < 4; ++mi)
                #pragma unroll
                for (int ni = 0; ni < 4; ++ni)
                    acc[mi][ni] = __builtin_amdgcn_mfma_f32_16x16x32_bf16(
                        af[mi], bf[ni], acc[mi][ni], 0, 0, 0);
        }
    }

    // epilogue: D layout col = lane&15, row = ko*4 + j
    float bv[4];
    #pragma unroll
    for (int ni = 0; ni < 4; ++ni) bv[ni] = bias[col0 + wc * 64 + ni * 16 + lr];
    #pragma unroll
    for (int mi = 0; mi < 4; ++mi)
        #pragma unroll
        for (int j = 0; j < 4; ++j) {
            const int grow = row0 + wr * 64 + mi * 16 + ko * 4 + j;
            #pragma unroll
            for (int ni = 0; ni < 4; ++ni) {
                const int gcol = col0 + wc * 64 + ni * 16 + lr;
                const float val = acc[mi][ni][j] + bv[ni];
                if (MODE == 0) {
                    ((float*)Cout)[(size_t)grow * CC + gcol] = val;
                } else {
                    const int hh = gcol >> 6, d = gcol & 63;
                    const int bb = grow >> 11, t = grow & 2047;
                    ((bf16_t*)Cout)[(((size_t)(bb * HH + hh)) * TT + t) * HS + d]
                        = (bf16_t)val;
                }
            }
        }
}

// ---------------------------------------------------------------------------
// Gated value transform (in-place):  v = (v + v@W1 + b1) * sigmoid(v@W2 + b2)
// ---------------------------------------------------------------------------
__global__ __launch_bounds__(256) void gate_kernel(
    float* __restrict__ v,
    const float* __restrict__ W1, const float* __restrict__ b1,
    const float* __restrict__ W2, const float* __restrict__ b2,
    int rows)
{
    __shared__ float W1s[64][65];
    __shared__ float W2s[64][65];
    __shared__ float b1s[64], b2s[64];
    __shared__ float vs[1024];
    const int tid = threadIdx.x;
    #pragma unroll
    for (int l = 0; l < 16; ++l) {
        int idx = tid + l * 256;
        W1s[idx >> 6][idx & 63] = W1[idx];
        W2s[idx >> 6][idx & 63] = W2[idx];
    }
    if (tid < 64) { b1s[tid] = b1[tid]; b2s[tid] = b2[tid]; }

    const int d = tid & 63;
    for (int row = blockIdx.x; row < rows; row += gridDim.x) {
        __syncthreads();
        for (int l = tid; l < 1024; l += 256) vs[l] = v[(size_t)row * 1024 + l];
        __syncthreads();
        for (int h = tid >> 6; h < 16; h += 4) {
            const float* vh = &vs[h * 64];
            float a = b1s[d], g = b2s[d];
            #pragma unroll 8
            for (int k = 0; k < 64; ++k) {
                a += vh[k] * W1s[k][d];
                g += vh[k] * W2s[k][d];
            }
            float val = (vh[d] + a) * (1.f / (1.f + __expf(-g)));
            v[(size_t)row * 1024 + h * 64 + d] = val;
        }
    }
}

// ---------------------------------------------------------------------------
// Pack: x fp32 [B,T,C] -> xb [B,H,T,64] bf16 ; v fp32 -> vbT [B,H,64,T] bf16
// ---------------------------------------------------------------------------
__global__ __launch_bounds__(256) void pack_kernel(
    const float* __restrict__ x, const float* __restrict__ v,
    bf16_t* __restrict__ xb, bf16_t* __restrict__ vbT)
{
    __shared__ float vs[64][65];
    const int tid = threadIdx.x;
    const int t0 = blockIdx.x * 64;
    const int h = blockIdx.y, b = blockIdx.z;
    const int c2 = (tid & 31) * 2;
    const int r  = tid >> 5;

    #pragma unroll
    for (int rr = r; rr < 64; rr += 8) {
        size_t src = ((size_t)b * TT + t0 + rr) * CC + (size_t)h * HS + c2;
        float2 xv = *reinterpret_cast<const float2*>(&x[src]);
        float2 vv = *reinterpret_cast<const float2*>(&v[src]);
        size_t dst = ((size_t)(b * HH + h) * TT + t0 + rr) * HS + c2;
        bf16x2 t;
        t[0] = (bf16_t)xv.x; t[1] = (bf16_t)xv.y;
        *reinterpret_cast<bf16x2*>(&xb[dst]) = t;
        vs[rr][c2] = vv.x; vs[rr][c2 + 1] = vv.y;
    }
    __syncthreads();
    #pragma unroll
    for (int d = r; d < 64; d += 8) {
        bf16x2 t;
        t[0] = (bf16_t)vs[c2][d];
        t[1] = (bf16_t)vs[c2 + 1][d];
        *reinterpret_cast<bf16x2*>(
            &vbT[((size_t)(b * HH + h) * HS + d) * TT + t0 + c2]) = t;
    }
}

// ---------------------------------------------------------------------------
// MFMA flash attention v2: 4 independent waves/block (NO barriers), each wave
// owns 32 q-rows; 64-key tiles; K/V frags from global (L2-resident); V loads
// issued before softmax to hide latency; P via per-wave padded LDS tile.
// Writes y directly as bf16 [ROWS, CC] for the final GEMM.
// ---------------------------------------------------------------------------
__global__ __launch_bounds__(256) void attn_mfma2_kernel(
    const bf16_t* __restrict__ ub, const bf16_t* __restrict__ xb,
    const bf16_t* __restrict__ vbT, bf16_t* __restrict__ ybf)
{
    __shared__ __align__(16) bf16_t Plds[4][32][72];
    const int tid = threadIdx.x, wave = tid >> 6, lane = tid & 63;
    const int qg = (int)(gridDim.x - 1 - blockIdx.x);   // heavy groups first
    const int h = blockIdx.y, b = blockIdx.z;
    const int q0 = qg * 128 + wave * 32;                // wave's first q row
    const size_t hQK = (size_t)(b * HH + h) * TT * HS;
    const size_t hVT = (size_t)(b * HH + h) * HS * TT;
    const int lr = lane & 15, ko = lane >> 4, lk = ko * 8;

    bf16x8 qf[2][2];
    #pragma unroll
    for (int mi = 0; mi < 2; ++mi)
        #pragma unroll
        for (int c = 0; c < 2; ++c)
            qf[mi][c] = *reinterpret_cast<const bf16x8*>(
                &ub[hQK + (size_t)(q0 + mi * 16 + lr) * HS + c * 32 + lk]);

    f32x4 O[2][4];
    float m_[2][4], l_[2][4];
    #pragma unroll
    for (int mi = 0; mi < 2; ++mi) {
        #pragma unroll
        for (int dt = 0; dt < 4; ++dt) O[mi][dt] = (f32x4){0.f, 0.f, 0.f, 0.f};
        #pragma unroll
        for (int j = 0; j < 4; ++j) { m_[mi][j] = -1e30f; l_[mi][j] = 0.f; }
    }

    const int ntiles = (q0 + 95) >> 6;   // ceil((q0+32)/64)
    for (int kt = 0; kt < ntiles; ++kt) {
        const int k0 = kt * 64;
        bf16x8 kf[4][2], vf[4][2];
        #pragma unroll
        for (int nt = 0; nt < 4; ++nt)
            #pragma unroll
            for (int c = 0; c < 2; ++c)
                kf[nt][c] = *reinterpret_cast<const bf16x8*>(
                    &xb[hQK + (size_t)(k0 + nt * 16 + lr) * HS + c * 32 + lk]);
        #pragma unroll
        for (int dt = 0; dt < 4; ++dt)
            #pragma unroll
            for (int c = 0; c < 2; ++c)
                vf[dt][c] = *reinterpret_cast<const bf16x8*>(
                    &vbT[hVT + (size_t)(dt * 16 + lr) * TT + k0 + c * 32 + lk]);

        // S = U @ X^T  (rows q, cols keys)
        f32x4 S[2][4];
        #pragma unroll
        for (int mi = 0; mi < 2; ++mi)
            #pragma unroll
            for (int nt = 0; nt < 4; ++nt) {
                f32x4 s = (f32x4){0.f, 0.f, 0.f, 0.f};
                s = __builtin_amdgcn_mfma_f32_16x16x32_bf16(qf[mi][0], kf[nt][0], s, 0, 0, 0);
                s = __builtin_amdgcn_mfma_f32_16x16x32_bf16(qf[mi][1], kf[nt][1], s, 0, 0, 0);
                S[mi][nt] = s;
            }

        const bool diag = (kt == ntiles - 1);
        #pragma unroll
        for (int mi = 0; mi < 2; ++mi)
            #pragma unroll
            for (int j = 0; j < 4; ++j) {
                const int qrel = mi * 16 + ko * 4 + j;
                const int qr = q0 + qrel;
                float mx = -1e30f;
                #pragma unroll
                for (int nt = 0; nt < 4; ++nt) {
                    float val = S[mi][nt][j] * 0.03125f;    // 1/sqrt(1024)
                    if (diag && (k0 + nt * 16 + lr) > qr) val = -1e30f;
                    S[mi][nt][j] = val;
                    mx = fmaxf(mx, val);
                }
                mx = fmaxf(mx, __shfl_xor(mx, 1));
                mx = fmaxf(mx, __shfl_xor(mx, 2));
                mx = fmaxf(mx, __shfl_xor(mx, 4));
                mx = fmaxf(mx, __shfl_xor(mx, 8));
                const float mnew = fmaxf(m_[mi][j], mx);
                const float sc = __expf(m_[mi][j] - mnew);
                float psum = 0.f;
                #pragma unroll
                for (int nt = 0; nt < 4; ++nt) {
                    float p = __expf(S[mi][nt][j] - mnew);
                    psum += p;
                    Plds[wave][qrel][nt * 16 + lr] = (bf16_t)p;
                }
                psum += __shfl_xor(psum, 1);
                psum += __shfl_xor(psum, 2);
                psum += __shfl_xor(psum, 4);
                psum += __shfl_xor(psum, 8);
                l_[mi][j] = l_[mi][j] * sc + psum;
                m_[mi][j] = mnew;
                #pragma unroll
                for (int dt = 0; dt < 4; ++dt) O[mi][dt][j] *= sc;
            }

        // O += P @ V^T-frags   (wave-internal LDS round-trip, no barrier)
        bf16x8 pa[2][2];
        #pragma unroll
        for (int mi = 0; mi < 2; ++mi)
            #pragma unroll
            for (int ks = 0; ks < 2; ++ks)
                pa[mi][ks] = *reinterpret_cast<const bf16x8*>(
                    &Plds[wave][mi * 16 + lr][ks * 32 + lk]);
        #pragma unroll
        for (int mi = 0; mi < 2; ++mi)
            #pragma unroll
            for (int dt = 0; dt < 4; ++dt) {
                O[mi][dt] = __builtin_amdgcn_mfma_f32_16x16x32_bf16(
                    pa[mi][0], vf[dt][0], O[mi][dt], 0, 0, 0);
                O[mi][dt] = __builtin_amdgcn_mfma_f32_16x16x32_bf16(
                    pa[mi][1], vf[dt][1], O[mi][dt], 0, 0, 0);
            }
    }

    // epilogue: ybf[b*T+q][h*64+d] = O / l   (bf16 for final GEMM)
    #pragma unroll
    for (int mi = 0; mi < 2; ++mi)
        #pragma unroll
        for (int j = 0; j < 4; ++j) {
            const float inv = 1.f / l_[mi][j];
            const size_t grow = (size_t)b * TT + q0 + mi * 16 + ko * 4 + j;
            #pragma unroll
            for (int dt = 0; dt < 4; ++dt)
                ybf[grow * CC + h * 64 + dt * 16 + lr] =
                    (bf16_t)(O[mi][dt][j] * inv);
        }
}

// ---------------------------------------------------------------------------
extern "C" void kernel_launch(void* const* d_in, const int* in_sizes, int n_in,
                              void* d_out, int out_size, void* d_ws, size_t ws_size,
                              hipStream_t stream)
{
    (void)in_sizes; (void)n_in; (void)out_size; (void)ws_size;
    const float* x  = (const float*)d_in[0];
    const float* Wu = (const float*)d_in[1];
    const float* bu = (const float*)d_in[2];
    const float* Wv = (const float*)d_in[3];
    const float* bv = (const float*)d_in[4];
    const float* W1 = (const float*)d_in[5];
    const float* b1 = (const float*)d_in[6];
    const float* W2 = (const float*)d_in[7];
    const float* b2 = (const float*)d_in[8];
    const float* Wp = (const float*)d_in[9];
    const float* bp = (const float*)d_in[10];
    float* out = (float*)d_out;

    const size_t NE = (size_t)ROWS * CC;
    float*  v   = (float*)d_ws;                     // 32 MB
    bf16_t* xbf = (bf16_t*)(v + NE);                // 16 MB
    bf16_t* WuT = xbf + NE;                         // 2 MB
    bf16_t* WvT = WuT + (size_t)CC * CC;            // 2 MB
    bf16_t* WpT = WvT + (size_t)CC * CC;            // 2 MB
    bf16_t* xb  = WpT + (size_t)CC * CC;            // 16 MB
    bf16_t* ubp = xb + NE;                          // 16 MB
    bf16_t* vbT = ubp + NE;                         // 16 MB
    bf16_t* ybf = xbf;                              // alias: xbf dead after GEMM2

    conv_x_kernel<<<ROWS * CC / (256 * 8), 256, 0, stream>>>(x, xbf);
    conv_wt_kernel<<<dim3(16, 16), 256, 0, stream>>>(Wu, WuT);
    conv_wt_kernel<<<dim3(16, 16), 256, 0, stream>>>(Wv, WvT);
    conv_wt_kernel<<<dim3(16, 16), 256, 0, stream>>>(Wp, WpT);

    dim3 gemm_grid(CC / 128, ROWS / 128);           // (8, 64)
    mfma_gemm_kernel<1><<<gemm_grid, 256, 0, stream>>>(xbf, WuT, bu, ubp);
    mfma_gemm_kernel<0><<<gemm_grid, 256, 0, stream>>>(xbf, WvT, bv, v);
    gate_kernel<<<2048, 256, 0, stream>>>(v, W1, b1, W2, b2, ROWS);
    pack_kernel<<<dim3(TT / 64, HH, BB), 256, 0, stream>>>(x, v, xb, vbT);
    attn_mfma2_kernel<<<dim3(TT / 128, HH, BB), 256, 0, stream>>>(ubp, xb, vbT, ybf);
    mfma_gemm_kernel<0><<<gemm_grid, 256, 0, stream>>>(ybf, WpT, bp, out);
}

// Round 4
// 376.187 us; speedup vs baseline: 5.7299x; 1.2131x over previous
//
#include <hip/hip_runtime.h>
#include <hip/hip_bf16.h>
#include <math.h>

// Problem constants (B=4, T=2048, C=1024, H=16, HS=64)
#define BB 4
#define TT 2048
#define CC 1024
#define HH 16
#define HS 64
#define ROWS (BB*TT)          // 8192

typedef __bf16 bf16_t;
typedef __bf16 bf16x8 __attribute__((ext_vector_type(8)));
typedef __bf16 bf16x4v __attribute__((ext_vector_type(4)));
typedef __bf16 bf16x2 __attribute__((ext_vector_type(2)));
typedef float  f32x4  __attribute__((ext_vector_type(4)));

// async global->LDS, 16B per lane; LDS dest is wave-uniform base + lane*16
#define GLDS16(g, l) __builtin_amdgcn_global_load_lds( \
    (const __attribute__((address_space(1))) void*)(g), \
    (__attribute__((address_space(3))) void*)(l), 16, 0, 0)

// ---------------------------------------------------------------------------
// fp32 -> bf16 convert (linear)
// ---------------------------------------------------------------------------
__global__ __launch_bounds__(256) void conv_x_kernel(
    const float* __restrict__ x, bf16_t* __restrict__ xbf)
{
    const size_t i = ((size_t)blockIdx.x * 256 + threadIdx.x) * 8;
    const float4 a = *reinterpret_cast<const float4*>(&x[i]);
    const float4 b = *reinterpret_cast<const float4*>(&x[i + 4]);
    bf16x8 o;
    o[0] = (bf16_t)a.x; o[1] = (bf16_t)a.y; o[2] = (bf16_t)a.z; o[3] = (bf16_t)a.w;
    o[4] = (bf16_t)b.x; o[5] = (bf16_t)b.y; o[6] = (bf16_t)b.z; o[7] = (bf16_t)b.w;
    *reinterpret_cast<bf16x8*>(&xbf[i]) = o;
}

// ---------------------------------------------------------------------------
// Weight transpose + convert:  Wt[n][k] = (bf16) W[k][n]     (1024x1024)
// ---------------------------------------------------------------------------
__global__ __launch_bounds__(256) void conv_wt_kernel(
    const float* __restrict__ W, bf16_t* __restrict__ Wt)
{
    __shared__ float t[64][65];
    const int tid = threadIdx.x;
    const int r0 = blockIdx.y * 64, c0 = blockIdx.x * 64;
    #pragma unroll
    for (int l = 0; l < 16; ++l) {
        int idx = tid + l * 256;            // 0..4095
        int rr = idx >> 6, cc = idx & 63;
        t[rr][cc] = W[(size_t)(r0 + rr) * CC + c0 + cc];
    }
    __syncthreads();
    #pragma unroll
    for (int l = 0; l < 16; ++l) {
        int idx = tid + l * 256;
        int rr = idx >> 6, cc = idx & 63;
        Wt[(size_t)(c0 + rr) * CC + r0 + cc] = (bf16_t)t[cc][rr];
    }
}

// ---------------------------------------------------------------------------
// MFMA GEMM (m97 structure): C[M,1024] = A[M,1024] @ W + bias
// ---------------------------------------------------------------------------
template<int MODE>
__global__ __launch_bounds__(256) void mfma_gemm_kernel(
    const bf16_t* __restrict__ A, const bf16_t* __restrict__ Bt,
    const float* __restrict__ bias, void* __restrict__ Cout)
{
    __shared__ uint32_t smem[(16384 + 16384) / 4];
    char* const sA = (char*)smem;            // [128 m][64 k] bf16, swizzled
    char* const sB = (char*)smem + 16384;    // [128 n][64 k] bf16, swizzled
    const int tid = threadIdx.x;
    const int wave = tid >> 6, lane = tid & 63;
    const int row0 = blockIdx.y * 128, col0 = blockIdx.x * 128;
    const int wr = wave >> 1, wc = wave & 1;
    const int lr = lane & 15, ko = lane >> 4;
    const int xorv = (lr & 7) << 4;                      // read-side swizzle
    const int koff = ((lane & 7) ^ (lane >> 3)) << 3;    // staging inverse swz
    const int mloc8 = lane >> 3;                         // staging row-in-8

    f32x4 acc[4][4];
    #pragma unroll
    for (int i = 0; i < 4; ++i)
        #pragma unroll
        for (int j = 0; j < 4; ++j) acc[i][j] = (f32x4){0.f, 0.f, 0.f, 0.f};

    for (int k0 = 0; k0 < 1024; k0 += 64) {
        if (k0) __syncthreads();
        #pragma unroll
        for (int a = 0; a < 4; ++a) {
            const int m = wave * 32 + a * 8 + mloc8;     // 0..127, each once
            GLDS16(A  + (size_t)(row0 + m) * CC + k0 + koff,
                   sA + (wave * 4 + a) * 1024);
            GLDS16(Bt + (size_t)(col0 + m) * CC + k0 + koff,
                   sB + (wave * 4 + a) * 1024);
        }
        asm volatile("s_waitcnt vmcnt(0)" ::: "memory");
        __syncthreads();
        #pragma unroll
        for (int ks = 0; ks < 2; ++ks) {
            bf16x8 af[4], bf[4];
            const int kb = (ks * 64 + ko * 16) ^ xorv;
            #pragma unroll
            for (int mi = 0; mi < 4; ++mi)
                af[mi] = *reinterpret_cast<const bf16x8*>(
                    sA + (wr * 64 + mi * 16 + lr) * 128 + kb);
            #pragma unroll
            for (int ni = 0; ni < 4; ++ni)
                bf[ni] = *reinterpret_cast<const bf16x8*>(
                    sB + (wc * 64 + ni * 16 + lr) * 128 + kb);
            #pragma unroll
            for (int mi = 0; mi < 4; ++mi)
                #pragma unroll
                for (int ni = 0; ni < 4; ++ni)
                    acc[mi][ni] = __builtin_amdgcn_mfma_f32_16x16x32_bf16(
                        af[mi], bf[ni], acc[mi][ni], 0, 0, 0);
        }
    }

    float bv[4];
    #pragma unroll
    for (int ni = 0; ni < 4; ++ni) bv[ni] = bias[col0 + wc * 64 + ni * 16 + lr];
    #pragma unroll
    for (int mi = 0; mi < 4; ++mi)
        #pragma unroll
        for (int j = 0; j < 4; ++j) {
            const int grow = row0 + wr * 64 + mi * 16 + ko * 4 + j;
            #pragma unroll
            for (int ni = 0; ni < 4; ++ni) {
                const int gcol = col0 + wc * 64 + ni * 16 + lr;
                const float val = acc[mi][ni][j] + bv[ni];
                if (MODE == 0) {
                    ((float*)Cout)[(size_t)grow * CC + gcol] = val;
                } else {
                    const int hh = gcol >> 6, d = gcol & 63;
                    const int bb = grow >> 11, t = grow & 2047;
                    ((bf16_t*)Cout)[(((size_t)(bb * HH + hh)) * TT + t) * HS + d]
                        = (bf16_t)val;
                }
            }
        }
}

// ---------------------------------------------------------------------------
// Gated value transform (in-place):  v = (v + v@W1 + b1) * sigmoid(v@W2 + b2)
// ---------------------------------------------------------------------------
__global__ __launch_bounds__(256) void gate_kernel(
    float* __restrict__ v,
    const float* __restrict__ W1, const float* __restrict__ b1,
    const float* __restrict__ W2, const float* __restrict__ b2,
    int rows)
{
    __shared__ float W1s[64][65];
    __shared__ float W2s[64][65];
    __shared__ float b1s[64], b2s[64];
    __shared__ float vs[1024];
    const int tid = threadIdx.x;
    #pragma unroll
    for (int l = 0; l < 16; ++l) {
        int idx = tid + l * 256;
        W1s[idx >> 6][idx & 63] = W1[idx];
        W2s[idx >> 6][idx & 63] = W2[idx];
    }
    if (tid < 64) { b1s[tid] = b1[tid]; b2s[tid] = b2[tid]; }

    const int d = tid & 63;
    for (int row = blockIdx.x; row < rows; row += gridDim.x) {
        __syncthreads();
        for (int l = tid; l < 1024; l += 256) vs[l] = v[(size_t)row * 1024 + l];
        __syncthreads();
        for (int h = tid >> 6; h < 16; h += 4) {
            const float* vh = &vs[h * 64];
            float a = b1s[d], g = b2s[d];
            #pragma unroll 8
            for (int k = 0; k < 64; ++k) {
                a += vh[k] * W1s[k][d];
                g += vh[k] * W2s[k][d];
            }
            float val = (vh[d] + a) * (1.f / (1.f + __expf(-g)));
            v[(size_t)row * 1024 + h * 64 + d] = val;
        }
    }
}

// ---------------------------------------------------------------------------
// Pack: x fp32 [B,T,C] -> xb [B,H,T,64] bf16 ; v fp32 -> vbT [B,H,64,T] bf16
// ---------------------------------------------------------------------------
__global__ __launch_bounds__(256) void pack_kernel(
    const float* __restrict__ x, const float* __restrict__ v,
    bf16_t* __restrict__ xb, bf16_t* __restrict__ vbT)
{
    __shared__ float vs[64][65];
    const int tid = threadIdx.x;
    const int t0 = blockIdx.x * 64;
    const int h = blockIdx.y, b = blockIdx.z;
    const int c2 = (tid & 31) * 2;
    const int r  = tid >> 5;

    #pragma unroll
    for (int rr = r; rr < 64; rr += 8) {
        size_t src = ((size_t)b * TT + t0 + rr) * CC + (size_t)h * HS + c2;
        float2 xv = *reinterpret_cast<const float2*>(&x[src]);
        float2 vv = *reinterpret_cast<const float2*>(&v[src]);
        size_t dst = ((size_t)(b * HH + h) * TT + t0 + rr) * HS + c2;
        bf16x2 t;
        t[0] = (bf16_t)xv.x; t[1] = (bf16_t)xv.y;
        *reinterpret_cast<bf16x2*>(&xb[dst]) = t;
        vs[rr][c2] = vv.x; vs[rr][c2 + 1] = vv.y;
    }
    __syncthreads();
    #pragma unroll
    for (int d = r; d < 64; d += 8) {
        bf16x2 t;
        t[0] = (bf16_t)vs[c2][d];
        t[1] = (bf16_t)vs[c2 + 1][d];
        *reinterpret_cast<bf16x2*>(
            &vbT[((size_t)(b * HH + h) * HS + d) * TT + t0 + c2]) = t;
    }
}

// ---------------------------------------------------------------------------
// MFMA flash attention v3: swapped QK^T (S^T, query = lane&15) -> in-register
// softmax (2 shfl per 16 queries); PV as O^T = mfma(V^T, P) so rescale and
// 1/l are lane-local; block-shared K/V^T LDS staging (XOR-swizzled, w=16
// global_load_lds), 2-phase double-buffered, one barrier per tile.
// 4 waves x 32 q-rows = 128-row q-block.
// ---------------------------------------------------------------------------
__global__ __launch_bounds__(256) void attn_mfma3_kernel(
    const bf16_t* __restrict__ ub, const bf16_t* __restrict__ xb,
    const bf16_t* __restrict__ vbT, bf16_t* __restrict__ ybf)
{
    __shared__ __align__(16) bf16_t KV[2][2][64][64];   // [buf][K|VT][row][col]
    __shared__ __align__(16) bf16_t Pl[4][32][72];      // per-wave P, swizzled

    const int tid = threadIdx.x, wave = tid >> 6, lane = tid & 63;
    const int qg = (int)(gridDim.x - 1 - blockIdx.x);   // heavy groups first
    const int h = blockIdx.y, b = blockIdx.z;
    const int q0 = qg * 128 + wave * 32;                // wave's first q row
    const size_t hQK = (size_t)(b * HH + h) * TT * HS;
    const size_t hVT = (size_t)(b * HH + h) * HS * TT;
    const int lr = lane & 15, ko = lane >> 4;
    const int koff = ((lane & 7) ^ (lane >> 3)) << 3;   // staging inverse swz
    const int rsub = lane >> 3;                          // staging row-in-8
    const bf16_t* const xh = xb + hQK;
    const bf16_t* const vh = vbT + hVT;
    char* const Pb = (char*)&Pl[wave][0][0];

    // Q fragments (B-operand of swapped QK): lane lr = query row
    bf16x8 qf[2][2];
    #pragma unroll
    for (int mi = 0; mi < 2; ++mi)
        #pragma unroll
        for (int c = 0; c < 2; ++c)
            qf[mi][c] = *reinterpret_cast<const bf16x8*>(
                &ub[hQK + (size_t)(q0 + mi * 16 + lr) * HS + c * 32 + ko * 8]);

    f32x4 O[2][4];                     // O^T: col=lane&15=q, row=ko*4+j=d
    float m_[2], l_[2];
    #pragma unroll
    for (int mi = 0; mi < 2; ++mi) {
        #pragma unroll
        for (int dt = 0; dt < 4; ++dt) O[mi][dt] = (f32x4){0.f, 0.f, 0.f, 0.f};
        m_[mi] = -1e30f; l_[mi] = 0.f;
    }

    const int myntiles = (q0 + 95) >> 6;
    const int maxtiles = 2 * qg + 2;

    // ---- stage tile 0
    #pragma unroll
    for (int i = 0; i < 2; ++i) {
        const int rb = (wave * 2 + i) * 8;
        GLDS16(xh + (size_t)(rb + rsub) * HS + koff, (char*)&KV[0][0][rb][0]);
        GLDS16(vh + (size_t)(rb + rsub) * TT + koff, (char*)&KV[0][1][rb][0]);
    }
    asm volatile("s_waitcnt vmcnt(0)" ::: "memory");
    __syncthreads();

    int buf = 0;
    for (int kt = 0; kt < maxtiles; ++kt) {
        const int k0 = kt * 64;
        // prefetch next tile into other buffer
        if (kt + 1 < maxtiles) {
            const int kn = k0 + 64;
            #pragma unroll
            for (int i = 0; i < 2; ++i) {
                const int rb = (wave * 2 + i) * 8;
                GLDS16(xh + (size_t)(kn + rb + rsub) * HS + koff,
                       (char*)&KV[buf ^ 1][0][rb][0]);
                GLDS16(vh + (size_t)(rb + rsub) * TT + kn + koff,
                       (char*)&KV[buf ^ 1][1][rb][0]);
            }
        }

        if (kt < myntiles) {
            char* const Kb = (char*)&KV[buf][0][0][0];
            char* const Vb = (char*)&KV[buf][1][0][0];
            // K fragments (A-operand): lane lr = key row
            bf16x8 kf[4][2];
            #pragma unroll
            for (int nt = 0; nt < 4; ++nt)
                #pragma unroll
                for (int c = 0; c < 2; ++c)
                    kf[nt][c] = *reinterpret_cast<const bf16x8*>(
                        Kb + (nt * 16 + lr) * 128 + ((((c << 2) + ko) ^ (lr & 7)) << 4));
            // S^T = K @ U^T : col=lane&15=query, row=ko*4+j=key
            f32x4 S[2][4];
            #pragma unroll
            for (int mi = 0; mi < 2; ++mi)
                #pragma unroll
                for (int nt = 0; nt < 4; ++nt) {
                    f32x4 s = (f32x4){0.f, 0.f, 0.f, 0.f};
                    s = __builtin_amdgcn_mfma_f32_16x16x32_bf16(kf[nt][0], qf[mi][0], s, 0, 0, 0);
                    s = __builtin_amdgcn_mfma_f32_16x16x32_bf16(kf[nt][1], qf[mi][1], s, 0, 0, 0);
                    S[mi][nt] = s;
                }

            const bool diag = (kt == myntiles - 1);
            float scl[2];
            #pragma unroll
            for (int mi = 0; mi < 2; ++mi) {
                const int qr = q0 + mi * 16 + lr;
                float mx = -1e30f;
                #pragma unroll
                for (int nt = 0; nt < 4; ++nt)
                    #pragma unroll
                    for (int j = 0; j < 4; ++j) {
                        float val = S[mi][nt][j] * 0.03125f;   // 1/sqrt(1024)
                        if (diag && (k0 + nt * 16 + ko * 4 + j) > qr) val = -1e30f;
                        S[mi][nt][j] = val;
                        mx = fmaxf(mx, val);
                    }
                mx = fmaxf(mx, __shfl_xor(mx, 16));
                mx = fmaxf(mx, __shfl_xor(mx, 32));
                const float mnew = fmaxf(m_[mi], mx);
                const float sc = __expf(m_[mi] - mnew);
                m_[mi] = mnew;
                float psum = 0.f;
                #pragma unroll
                for (int nt = 0; nt < 4; ++nt) {
                    bf16x4v pw;
                    #pragma unroll
                    for (int j = 0; j < 4; ++j) {
                        float p = __expf(S[mi][nt][j] - mnew);
                        psum += p;
                        pw[j] = (bf16_t)p;
                    }
                    // write P[q][k]: chunk = nt*2+(ko>>1) ^ (q&7), sub = (ko&1)*8
                    *reinterpret_cast<bf16x4v*>(
                        Pb + (mi * 16 + lr) * 144 +
                        ((((nt << 1) + (ko >> 1)) ^ (lr & 7)) << 4) + ((ko & 1) << 3)) = pw;
                }
                psum += __shfl_xor(psum, 16);
                psum += __shfl_xor(psum, 32);
                l_[mi] = l_[mi] * sc + psum;
                scl[mi] = sc;
            }
            // rescale O^T (lane-local: all regs of lane belong to query lr)
            #pragma unroll
            for (int mi = 0; mi < 2; ++mi)
                #pragma unroll
                for (int dt = 0; dt < 4; ++dt)
                    #pragma unroll
                    for (int j = 0; j < 4; ++j) O[mi][dt][j] *= scl[mi];

            // O^T += V^T @ P^T : A = V^T rows d, B = P rows q
            bf16x8 vt[4][2], pf[2][2];
            #pragma unroll
            for (int dt = 0; dt < 4; ++dt)
                #pragma unroll
                for (int c = 0; c < 2; ++c)
                    vt[dt][c] = *reinterpret_cast<const bf16x8*>(
                        Vb + (dt * 16 + lr) * 128 + ((((c << 2) + ko) ^ (lr & 7)) << 4));
            #pragma unroll
            for (int mi = 0; mi < 2; ++mi)
                #pragma unroll
                for (int ks = 0; ks < 2; ++ks)
                    pf[mi][ks] = *reinterpret_cast<const bf16x8*>(
                        Pb + (mi * 16 + lr) * 144 + ((((ks << 2) + ko) ^ (lr & 7)) << 4));
            #pragma unroll
            for (int mi = 0; mi < 2; ++mi)
                #pragma unroll
                for (int dt = 0; dt < 4; ++dt) {
                    O[mi][dt] = __builtin_amdgcn_mfma_f32_16x16x32_bf16(
                        vt[dt][0], pf[mi][0], O[mi][dt], 0, 0, 0);
                    O[mi][dt] = __builtin_amdgcn_mfma_f32_16x16x32_bf16(
                        vt[dt][1], pf[mi][1], O[mi][dt], 0, 0, 0);
                }
        }

        asm volatile("s_waitcnt vmcnt(0)" ::: "memory");
        __syncthreads();
        buf ^= 1;
    }

    // epilogue: lane holds query q0+mi*16+lr, d = dt*16+ko*4+j
    #pragma unroll
    for (int mi = 0; mi < 2; ++mi) {
        const float inv = 1.f / l_[mi];
        const size_t grow = (size_t)b * TT + q0 + mi * 16 + lr;
        #pragma unroll
        for (int dt = 0; dt < 4; ++dt) {
            bf16x4v o4;
            #pragma unroll
            for (int j = 0; j < 4; ++j) o4[j] = (bf16_t)(O[mi][dt][j] * inv);
            *reinterpret_cast<bf16x4v*>(
                &ybf[grow * CC + h * 64 + dt * 16 + ko * 4]) = o4;
        }
    }
}

// ---------------------------------------------------------------------------
extern "C" void kernel_launch(void* const* d_in, const int* in_sizes, int n_in,
                              void* d_out, int out_size, void* d_ws, size_t ws_size,
                              hipStream_t stream)
{
    (void)in_sizes; (void)n_in; (void)out_size; (void)ws_size;
    const float* x  = (const float*)d_in[0];
    const float* Wu = (const float*)d_in[1];
    const float* bu = (const float*)d_in[2];
    const float* Wv = (const float*)d_in[3];
    const float* bv = (const float*)d_in[4];
    const float* W1 = (const float*)d_in[5];
    const float* b1 = (const float*)d_in[6];
    const float* W2 = (const float*)d_in[7];
    const float* b2 = (const float*)d_in[8];
    const float* Wp = (const float*)d_in[9];
    const float* bp = (const float*)d_in[10];
    float* out = (float*)d_out;

    const size_t NE = (size_t)ROWS * CC;
    float*  v   = (float*)d_ws;                     // 32 MB
    bf16_t* xbf = (bf16_t*)(v + NE);                // 16 MB
    bf16_t* WuT = xbf + NE;                         // 2 MB
    bf16_t* WvT = WuT + (size_t)CC * CC;            // 2 MB
    bf16_t* WpT = WvT + (size_t)CC * CC;            // 2 MB
    bf16_t* xb  = WpT + (size_t)CC * CC;            // 16 MB
    bf16_t* ubp = xb + NE;                          // 16 MB
    bf16_t* vbT = ubp + NE;                         // 16 MB
    bf16_t* ybf = xbf;                              // alias: xbf dead after GEMM2

    conv_x_kernel<<<ROWS * CC / (256 * 8), 256, 0, stream>>>(x, xbf);
    conv_wt_kernel<<<dim3(16, 16), 256, 0, stream>>>(Wu, WuT);
    conv_wt_kernel<<<dim3(16, 16), 256, 0, stream>>>(Wv, WvT);
    conv_wt_kernel<<<dim3(16, 16), 256, 0, stream>>>(Wp, WpT);

    dim3 gemm_grid(CC / 128, ROWS / 128);           // (8, 64)
    mfma_gemm_kernel<1><<<gemm_grid, 256, 0, stream>>>(xbf, WuT, bu, ubp);
    mfma_gemm_kernel<0><<<gemm_grid, 256, 0, stream>>>(xbf, WvT, bv, v);
    gate_kernel<<<2048, 256, 0, stream>>>(v, W1, b1, W2, b2, ROWS);
    pack_kernel<<<dim3(TT / 64, HH, BB), 256, 0, stream>>>(x, v, xb, vbT);
    attn_mfma3_kernel<<<dim3(TT / 128, HH, BB), 256, 0, stream>>>(ubp, xb, vbT, ybf);
    mfma_gemm_kernel<0><<<gemm_grid, 256, 0, stream>>>(ybf, WpT, bp, out);
}

// Round 5
// 276.710 us; speedup vs baseline: 7.7898x; 1.3595x over previous
//
#include <hip/hip_runtime.h>
#include <hip/hip_bf16.h>
#include <math.h>

// Problem constants (B=4, T=2048, C=1024, H=16, HS=64)
#define BB 4
#define TT 2048
#define CC 1024
#define HH 16
#define HS 64
#define ROWS (BB*TT)          // 8192

typedef __bf16 bf16_t;
typedef __bf16 bf16x8 __attribute__((ext_vector_type(8)));
typedef __bf16 bf16x4v __attribute__((ext_vector_type(4)));
typedef float  f32x4  __attribute__((ext_vector_type(4)));

// async global->LDS, 16B per lane; LDS dest is wave-uniform base + lane*16
#define GLDS16(g, l) __builtin_amdgcn_global_load_lds( \
    (const __attribute__((address_space(1))) void*)(g), \
    (__attribute__((address_space(3))) void*)(l), 16, 0, 0)

// ---------------------------------------------------------------------------
// fp32 -> bf16 convert (linear)
// ---------------------------------------------------------------------------
__global__ __launch_bounds__(256) void conv_x_kernel(
    const float* __restrict__ x, bf16_t* __restrict__ xbf)
{
    const size_t i = ((size_t)blockIdx.x * 256 + threadIdx.x) * 8;
    const float4 a = *reinterpret_cast<const float4*>(&x[i]);
    const float4 b = *reinterpret_cast<const float4*>(&x[i + 4]);
    bf16x8 o;
    o[0] = (bf16_t)a.x; o[1] = (bf16_t)a.y; o[2] = (bf16_t)a.z; o[3] = (bf16_t)a.w;
    o[4] = (bf16_t)b.x; o[5] = (bf16_t)b.y; o[6] = (bf16_t)b.z; o[7] = (bf16_t)b.w;
    *reinterpret_cast<bf16x8*>(&xbf[i]) = o;
}

// ---------------------------------------------------------------------------
// Weight transpose + convert:  Wt[n][k] = (bf16) W[k][n]     (1024x1024)
// ---------------------------------------------------------------------------
__global__ __launch_bounds__(256) void conv_wt_kernel(
    const float* __restrict__ W, bf16_t* __restrict__ Wt)
{
    __shared__ float t[64][65];
    const int tid = threadIdx.x;
    const int r0 = blockIdx.y * 64, c0 = blockIdx.x * 64;
    #pragma unroll
    for (int l = 0; l < 16; ++l) {
        int idx = tid + l * 256;            // 0..4095
        int rr = idx >> 6, cc = idx & 63;
        t[rr][cc] = W[(size_t)(r0 + rr) * CC + c0 + cc];
    }
    __syncthreads();
    #pragma unroll
    for (int l = 0; l < 16; ++l) {
        int idx = tid + l * 256;
        int rr = idx >> 6, cc = idx & 63;
        Wt[(size_t)(c0 + rr) * CC + r0 + cc] = (bf16_t)t[cc][rr];
    }
}

// ---------------------------------------------------------------------------
// W1/W2 (64x64 fp32) -> transposed bf16:  WT[n][k] = (bf16) W[k][n]
// ---------------------------------------------------------------------------
__global__ __launch_bounds__(256) void conv_w64_kernel(
    const float* __restrict__ W1, const float* __restrict__ W2,
    bf16_t* __restrict__ W1T, bf16_t* __restrict__ W2T)
{
    __shared__ float t1[64][65], t2[64][65];
    const int tid = threadIdx.x;
    #pragma unroll
    for (int l = 0; l < 16; ++l) {
        int idx = tid + l * 256;
        int rr = idx >> 6, cc = idx & 63;
        t1[rr][cc] = W1[idx]; t2[rr][cc] = W2[idx];
    }
    __syncthreads();
    #pragma unroll
    for (int l = 0; l < 16; ++l) {
        int idx = tid + l * 256;
        int rr = idx >> 6, cc = idx & 63;
        W1T[idx] = (bf16_t)t1[cc][rr];
        W2T[idx] = (bf16_t)t2[cc][rr];
    }
}

// ---------------------------------------------------------------------------
// MFMA GEMM (m97 structure): C[M,1024] = A[M,1024] @ W + bias
//   MODE 0: fp32 linear out.  MODE 1: bf16 linear out.
// ---------------------------------------------------------------------------
template<int MODE>
__global__ __launch_bounds__(256) void mfma_gemm_kernel(
    const bf16_t* __restrict__ A, const bf16_t* __restrict__ Bt,
    const float* __restrict__ bias, void* __restrict__ Cout)
{
    __shared__ uint32_t smem[(16384 + 16384) / 4];
    char* const sA = (char*)smem;            // [128 m][64 k] bf16, swizzled
    char* const sB = (char*)smem + 16384;    // [128 n][64 k] bf16, swizzled
    const int tid = threadIdx.x;
    const int wave = tid >> 6, lane = tid & 63;
    const int row0 = blockIdx.y * 128, col0 = blockIdx.x * 128;
    const int wr = wave >> 1, wc = wave & 1;
    const int lr = lane & 15, ko = lane >> 4;
    const int xorv = (lr & 7) << 4;                      // read-side swizzle
    const int koff = ((lane & 7) ^ (lane >> 3)) << 3;    // staging inverse swz
    const int mloc8 = lane >> 3;                         // staging row-in-8

    f32x4 acc[4][4];
    #pragma unroll
    for (int i = 0; i < 4; ++i)
        #pragma unroll
        for (int j = 0; j < 4; ++j) acc[i][j] = (f32x4){0.f, 0.f, 0.f, 0.f};

    for (int k0 = 0; k0 < 1024; k0 += 64) {
        if (k0) __syncthreads();
        #pragma unroll
        for (int a = 0; a < 4; ++a) {
            const int m = wave * 32 + a * 8 + mloc8;     // 0..127, each once
            GLDS16(A  + (size_t)(row0 + m) * CC + k0 + koff,
                   sA + (wave * 4 + a) * 1024);
            GLDS16(Bt + (size_t)(col0 + m) * CC + k0 + koff,
                   sB + (wave * 4 + a) * 1024);
        }
        asm volatile("s_waitcnt vmcnt(0)" ::: "memory");
        __syncthreads();
        #pragma unroll
        for (int ks = 0; ks < 2; ++ks) {
            bf16x8 af[4], bfr[4];
            const int kb = (ks * 64 + ko * 16) ^ xorv;
            #pragma unroll
            for (int mi = 0; mi < 4; ++mi)
                af[mi] = *reinterpret_cast<const bf16x8*>(
                    sA + (wr * 64 + mi * 16 + lr) * 128 + kb);
            #pragma unroll
            for (int ni = 0; ni < 4; ++ni)
                bfr[ni] = *reinterpret_cast<const bf16x8*>(
                    sB + (wc * 64 + ni * 16 + lr) * 128 + kb);
            #pragma unroll
            for (int mi = 0; mi < 4; ++mi)
                #pragma unroll
                for (int ni = 0; ni < 4; ++ni)
                    acc[mi][ni] = __builtin_amdgcn_mfma_f32_16x16x32_bf16(
                        af[mi], bfr[ni], acc[mi][ni], 0, 0, 0);
        }
    }

    float bv[4];
    #pragma unroll
    for (int ni = 0; ni < 4; ++ni) bv[ni] = bias[col0 + wc * 64 + ni * 16 + lr];
    #pragma unroll
    for (int mi = 0; mi < 4; ++mi)
        #pragma unroll
        for (int j = 0; j < 4; ++j) {
            const int grow = row0 + wr * 64 + mi * 16 + ko * 4 + j;
            #pragma unroll
            for (int ni = 0; ni < 4; ++ni) {
                const int gcol = col0 + wc * 64 + ni * 16 + lr;
                const float val = acc[mi][ni][j] + bv[ni];
                if (MODE == 0)
                    ((float*)Cout)[(size_t)grow * CC + gcol] = val;
                else
                    ((bf16_t*)Cout)[(size_t)grow * CC + gcol] = (bf16_t)val;
            }
        }
}

// ---------------------------------------------------------------------------
// MFMA gated transform, transposed output:
//   per head-row v (64): out = (v + v@W1 + b1) * sigmoid(v@W2 + b2)
//   computed swapped (A=W^T frags rows=d, B=V frags cols=t) so D = out^T and
//   the write to vbT [B*H, 64, TT] is direct.
// Block = 64 t-rows x 1 head; 4 waves x 16 t-cols.
// ---------------------------------------------------------------------------
__global__ __launch_bounds__(256) void gate_mfma_kernel(
    const bf16_t* __restrict__ vp,      // [ROWS][CC] bf16
    const bf16_t* __restrict__ W1T, const bf16_t* __restrict__ W2T,
    const float* __restrict__ b1, const float* __restrict__ b2,
    bf16_t* __restrict__ vbT)           // [B*H][64][TT]
{
    __shared__ __align__(16) bf16_t Vs[64][64];   // XOR-swizzled rows
    const int tid = threadIdx.x, wave = tid >> 6, lane = tid & 63;
    const int t0 = blockIdx.x * 64;               // global row tile
    const int h = blockIdx.y;
    const int lr = lane & 15, ko = lane >> 4;
    const int koff = ((lane & 7) ^ (lane >> 3)) << 3;
    const int rsub = lane >> 3;

    #pragma unroll
    for (int i = 0; i < 2; ++i) {
        const int rb = (wave * 2 + i) * 8;
        GLDS16(vp + (size_t)(t0 + rb + rsub) * CC + h * 64 + koff,
               (char*)&Vs[rb][0]);
    }
    asm volatile("s_waitcnt vmcnt(0)" ::: "memory");
    __syncthreads();

    // A-frags: W^T rows = d
    bf16x8 w1f[4][2], w2f[4][2];
    #pragma unroll
    for (int ni = 0; ni < 4; ++ni)
        #pragma unroll
        for (int kc = 0; kc < 2; ++kc) {
            w1f[ni][kc] = *reinterpret_cast<const bf16x8*>(
                &W1T[(ni * 16 + lr) * 64 + kc * 32 + ko * 8]);
            w2f[ni][kc] = *reinterpret_cast<const bf16x8*>(
                &W2T[(ni * 16 + lr) * 64 + kc * 32 + ko * 8]);
        }
    // B-frags: V rows = t (this wave's 16 cols)
    const int trow = wave * 16 + lr;
    bf16x8 vf[2];
    #pragma unroll
    for (int kc = 0; kc < 2; ++kc)
        vf[kc] = *reinterpret_cast<const bf16x8*>(
            (char*)Vs + trow * 128 + ((((kc << 2) + ko) ^ (trow & 7)) << 4));

    f32x4 Aacc[4], Gacc[4];
    #pragma unroll
    for (int ni = 0; ni < 4; ++ni) {
        Aacc[ni] = (f32x4){0.f, 0.f, 0.f, 0.f};
        Gacc[ni] = (f32x4){0.f, 0.f, 0.f, 0.f};
    }
    #pragma unroll
    for (int ni = 0; ni < 4; ++ni)
        #pragma unroll
        for (int kc = 0; kc < 2; ++kc) {
            Aacc[ni] = __builtin_amdgcn_mfma_f32_16x16x32_bf16(
                w1f[ni][kc], vf[kc], Aacc[ni], 0, 0, 0);
            Gacc[ni] = __builtin_amdgcn_mfma_f32_16x16x32_bf16(
                w2f[ni][kc], vf[kc], Gacc[ni], 0, 0, 0);
        }

    // epilogue: lane holds col t = t0+trow, rows d = ni*16+ko*4+j
    const int bidx = t0 >> 11;                    // batch
    const int tb = (t0 & 2047) + trow;            // t within batch
    const size_t obase = (size_t)(bidx * HH + h) * HS * TT;
    #pragma unroll
    for (int ni = 0; ni < 4; ++ni)
        #pragma unroll
        for (int j = 0; j < 4; ++j) {
            const int d = ni * 16 + ko * 4 + j;
            const float vterm = (float)*(const bf16_t*)(
                (const char*)Vs + trow * 128 +
                ((((d >> 3) ^ (trow & 7)) << 4) + (d & 7) * 2));
            const float a = Aacc[ni][j] + b1[d];
            const float g = Gacc[ni][j] + b2[d];
            const float val = (vterm + a) * (1.f / (1.f + __expf(-g)));
            vbT[obase + (size_t)d * TT + tb] = (bf16_t)val;
        }
}

// ---------------------------------------------------------------------------
// MFMA flash attention v4: swapped QK^T softmax; KV LDS staging (2-phase
// double buffer); P tile now 128B-stride XOR-swizzled (conflict-free).
// Q/K read from linear [ROWS][CC] bf16; V^T from vbT. 4 waves x 32 q.
// ---------------------------------------------------------------------------
__global__ __launch_bounds__(256) void attn_mfma4_kernel(
    const bf16_t* __restrict__ ubf, const bf16_t* __restrict__ xbf,
    const bf16_t* __restrict__ vbT, bf16_t* __restrict__ ybf)
{
    __shared__ __align__(16) bf16_t KV[2][2][64][64];   // [buf][K|VT][row][64]
    __shared__ __align__(16) bf16_t Pl[4][32][64];      // per-wave P^T[q][k]

    const int tid = threadIdx.x, wave = tid >> 6, lane = tid & 63;
    const int qg = (int)(gridDim.x - 1 - blockIdx.x);   // heavy groups first
    const int h = blockIdx.y, b = blockIdx.z;
    const int q0 = qg * 128 + wave * 32;
    const size_t rbase = (size_t)b * TT;                // row base in [ROWS][CC]
    const int hcol = h * 64;
    const size_t hVT = (size_t)(b * HH + h) * HS * TT;
    const int lr = lane & 15, ko = lane >> 4;
    const int koff = ((lane & 7) ^ (lane >> 3)) << 3;
    const int rsub = lane >> 3;
    char* const Pb = (char*)&Pl[wave][0][0];

    // Q fragments (B-operand of swapped QK): lane lr = query row
    bf16x8 qf[2][2];
    #pragma unroll
    for (int mi = 0; mi < 2; ++mi)
        #pragma unroll
        for (int c = 0; c < 2; ++c)
            qf[mi][c] = *reinterpret_cast<const bf16x8*>(
                &ubf[(rbase + q0 + mi * 16 + lr) * CC + hcol + c * 32 + ko * 8]);

    f32x4 O[2][4];                     // O^T: col=lane&15=q, row=ko*4+j=d
    float m_[2], l_[2];
    #pragma unroll
    for (int mi = 0; mi < 2; ++mi) {
        #pragma unroll
        for (int dt = 0; dt < 4; ++dt) O[mi][dt] = (f32x4){0.f, 0.f, 0.f, 0.f};
        m_[mi] = -1e30f; l_[mi] = 0.f;
    }

    const int myntiles = (q0 + 95) >> 6;
    const int maxtiles = 2 * qg + 2;

    // ---- stage tile 0
    #pragma unroll
    for (int i = 0; i < 2; ++i) {
        const int rb = (wave * 2 + i) * 8;
        GLDS16(xbf + (rbase + rb + rsub) * CC + hcol + koff, (char*)&KV[0][0][rb][0]);
        GLDS16(vbT + hVT + (size_t)(rb + rsub) * TT + koff,  (char*)&KV[0][1][rb][0]);
    }
    asm volatile("s_waitcnt vmcnt(0)" ::: "memory");
    __syncthreads();

    int buf = 0;
    for (int kt = 0; kt < maxtiles; ++kt) {
        const int k0 = kt * 64;
        if (kt + 1 < maxtiles) {
            const int kn = k0 + 64;
            #pragma unroll
            for (int i = 0; i < 2; ++i) {
                const int rb = (wave * 2 + i) * 8;
                GLDS16(xbf + (rbase + kn + rb + rsub) * CC + hcol + koff,
                       (char*)&KV[buf ^ 1][0][rb][0]);
                GLDS16(vbT + hVT + (size_t)(rb + rsub) * TT + kn + koff,
                       (char*)&KV[buf ^ 1][1][rb][0]);
            }
        }

        if (kt < myntiles) {
            char* const Kb = (char*)&KV[buf][0][0][0];
            char* const Vb = (char*)&KV[buf][1][0][0];
            bf16x8 kf[4][2];
            #pragma unroll
            for (int nt = 0; nt < 4; ++nt)
                #pragma unroll
                for (int c = 0; c < 2; ++c)
                    kf[nt][c] = *reinterpret_cast<const bf16x8*>(
                        Kb + (nt * 16 + lr) * 128 + ((((c << 2) + ko) ^ (lr & 7)) << 4));
            // S^T = K @ U^T : col=query, row=key
            f32x4 S[2][4];
            #pragma unroll
            for (int mi = 0; mi < 2; ++mi)
                #pragma unroll
                for (int nt = 0; nt < 4; ++nt) {
                    f32x4 s = (f32x4){0.f, 0.f, 0.f, 0.f};
                    s = __builtin_amdgcn_mfma_f32_16x16x32_bf16(kf[nt][0], qf[mi][0], s, 0, 0, 0);
                    s = __builtin_amdgcn_mfma_f32_16x16x32_bf16(kf[nt][1], qf[mi][1], s, 0, 0, 0);
                    S[mi][nt] = s;
                }

            const bool diag = (kt == myntiles - 1);
            float scl[2];
            #pragma unroll
            for (int mi = 0; mi < 2; ++mi) {
                const int qr = q0 + mi * 16 + lr;
                float mx = -1e30f;
                #pragma unroll
                for (int nt = 0; nt < 4; ++nt)
                    #pragma unroll
                    for (int j = 0; j < 4; ++j) {
                        float val = S[mi][nt][j] * 0.03125f;   // 1/sqrt(1024)
                        if (diag && (k0 + nt * 16 + ko * 4 + j) > qr) val = -1e30f;
                        S[mi][nt][j] = val;
                        mx = fmaxf(mx, val);
                    }
                mx = fmaxf(mx, __shfl_xor(mx, 16));
                mx = fmaxf(mx, __shfl_xor(mx, 32));
                const float mnew = fmaxf(m_[mi], mx);
                const float sc = __expf(m_[mi] - mnew);
                m_[mi] = mnew;
                float psum = 0.f;
                #pragma unroll
                for (int nt = 0; nt < 4; ++nt) {
                    bf16x4v pw;
                    #pragma unroll
                    for (int j = 0; j < 4; ++j) {
                        float p = __expf(S[mi][nt][j] - mnew);
                        psum += p;
                        pw[j] = (bf16_t)p;
                    }
                    // P^T[q][k], 128B rows, chunk ^= (q&7): conflict-free
                    *reinterpret_cast<bf16x4v*>(
                        Pb + (mi * 16 + lr) * 128 +
                        ((((nt << 1) + (ko >> 1)) ^ (lr & 7)) << 4) + ((ko & 1) << 3)) = pw;
                }
                psum += __shfl_xor(psum, 16);
                psum += __shfl_xor(psum, 32);
                l_[mi] = l_[mi] * sc + psum;
                scl[mi] = sc;
            }
            #pragma unroll
            for (int mi = 0; mi < 2; ++mi)
                #pragma unroll
                for (int dt = 0; dt < 4; ++dt)
                    #pragma unroll
                    for (int j = 0; j < 4; ++j) O[mi][dt][j] *= scl[mi];

            // O^T += V^T @ P^T
            bf16x8 vt[4][2], pf[2][2];
            #pragma unroll
            for (int dt = 0; dt < 4; ++dt)
                #pragma unroll
                for (int c = 0; c < 2; ++c)
                    vt[dt][c] = *reinterpret_cast<const bf16x8*>(
                        Vb + (dt * 16 + lr) * 128 + ((((c << 2) + ko) ^ (lr & 7)) << 4));
            #pragma unroll
            for (int mi = 0; mi < 2; ++mi)
                #pragma unroll
                for (int ks = 0; ks < 2; ++ks)
                    pf[mi][ks] = *reinterpret_cast<const bf16x8*>(
                        Pb + (mi * 16 + lr) * 128 + ((((ks << 2) + ko) ^ (lr & 7)) << 4));
            #pragma unroll
            for (int mi = 0; mi < 2; ++mi)
                #pragma unroll
                for (int dt = 0; dt < 4; ++dt) {
                    O[mi][dt] = __builtin_amdgcn_mfma_f32_16x16x32_bf16(
                        vt[dt][0], pf[mi][0], O[mi][dt], 0, 0, 0);
                    O[mi][dt] = __builtin_amdgcn_mfma_f32_16x16x32_bf16(
                        vt[dt][1], pf[mi][1], O[mi][dt], 0, 0, 0);
                }
        }

        asm volatile("s_waitcnt vmcnt(0)" ::: "memory");
        __syncthreads();
        buf ^= 1;
    }

    // epilogue: lane holds query q0+mi*16+lr, d = dt*16+ko*4+j
    #pragma unroll
    for (int mi = 0; mi < 2; ++mi) {
        const float inv = 1.f / l_[mi];
        const size_t grow = rbase + q0 + mi * 16 + lr;
        #pragma unroll
        for (int dt = 0; dt < 4; ++dt) {
            bf16x4v o4;
            #pragma unroll
            for (int j = 0; j < 4; ++j) o4[j] = (bf16_t)(O[mi][dt][j] * inv);
            *reinterpret_cast<bf16x4v*>(
                &ybf[grow * CC + hcol + dt * 16 + ko * 4]) = o4;
        }
    }
}

// ---------------------------------------------------------------------------
extern "C" void kernel_launch(void* const* d_in, const int* in_sizes, int n_in,
                              void* d_out, int out_size, void* d_ws, size_t ws_size,
                              hipStream_t stream)
{
    (void)in_sizes; (void)n_in; (void)out_size; (void)ws_size;
    const float* x  = (const float*)d_in[0];
    const float* Wu = (const float*)d_in[1];
    const float* bu = (const float*)d_in[2];
    const float* Wv = (const float*)d_in[3];
    const float* bv = (const float*)d_in[4];
    const float* W1 = (const float*)d_in[5];
    const float* b1 = (const float*)d_in[6];
    const float* W2 = (const float*)d_in[7];
    const float* b2 = (const float*)d_in[8];
    const float* Wp = (const float*)d_in[9];
    const float* bp = (const float*)d_in[10];
    float* out = (float*)d_out;

    const size_t NE = (size_t)ROWS * CC;
    bf16_t* xbf = (bf16_t*)d_ws;                    // 16 MB
    bf16_t* ubf = xbf + NE;                         // 16 MB
    bf16_t* vp  = ubf + NE;                         // 16 MB
    bf16_t* vbT = vp  + NE;                         // 16 MB
    bf16_t* WuT = vbT + NE;                         // 2 MB
    bf16_t* WvT = WuT + (size_t)CC * CC;            // 2 MB
    bf16_t* WpT = WvT + (size_t)CC * CC;            // 2 MB
    bf16_t* W1T = WpT + (size_t)CC * CC;            // 8 KB
    bf16_t* W2T = W1T + (size_t)HS * HS;            // 8 KB
    bf16_t* ybf = vp;                               // alias: vp dead after gate

    conv_x_kernel<<<ROWS * CC / (256 * 8), 256, 0, stream>>>(x, xbf);
    conv_wt_kernel<<<dim3(16, 16), 256, 0, stream>>>(Wu, WuT);
    conv_wt_kernel<<<dim3(16, 16), 256, 0, stream>>>(Wv, WvT);
    conv_wt_kernel<<<dim3(16, 16), 256, 0, stream>>>(Wp, WpT);
    conv_w64_kernel<<<1, 256, 0, stream>>>(W1, W2, W1T, W2T);

    dim3 gemm_grid(CC / 128, ROWS / 128);           // (8, 64)
    mfma_gemm_kernel<1><<<gemm_grid, 256, 0, stream>>>(xbf, WuT, bu, ubf);
    mfma_gemm_kernel<1><<<gemm_grid, 256, 0, stream>>>(xbf, WvT, bv, vp);
    gate_mfma_kernel<<<dim3(ROWS / 64, HH), 256, 0, stream>>>(
        vp, W1T, W2T, b1, b2, vbT);
    attn_mfma4_kernel<<<dim3(TT / 128, HH, BB), 256, 0, stream>>>(
        ubf, xbf, vbT, ybf);
    mfma_gemm_kernel<0><<<gemm_grid, 256, 0, stream>>>(ybf, WpT, bp, out);
}